// Round 7
// baseline (355.844 us; speedup 1.0000x reference)
//
#include <hip/hip_runtime.h>
#include <stdint.h>

// B=1024, T=65, D=H=512. Only the SLOW critic feeds the output.
//   prep:  W1s,W2s -> bf16 transposed Wt[n][k]; zero tarval
//   gemm1: H1 = silu(feat @ W1s + b1s)           BK=32 dbuf, counted vmcnt
//   gemm2: tarval = silu(H1 @ W2s + b2s) @ W3s   same, fused W3 reduce
//   scan:  lambda-return suffix scan (log-depth shuffle) -> out (f32)
// BK=32: LDS 32KB total -> 4 blocks/CU (launch_bounds(256,4)); 64B row
// stride makes ds_read_b128 conflict-free WITHOUT swizzle (granule class
// alternates {q,q+4} per row -> perfect 8-per-class spread).

#define MROWS 66560   // 1024*65
#define RBLK 520      // MROWS/128
#define LAMF 0.95f
#define DISCF ((float)(1.0 - 1.0 / 333.0))

typedef __attribute__((ext_vector_type(8))) __bf16 bf16x8;
typedef __attribute__((ext_vector_type(4))) float f32x4;
typedef __attribute__((ext_vector_type(4))) unsigned int u32x4;

__device__ __forceinline__ unsigned short f2bf(float f) {
  unsigned int u = __float_as_uint(f);
  return (unsigned short)((u + 0x7FFFu + ((u >> 16) & 1u)) >> 16);
}
__device__ __forceinline__ float silu_f(float x) { return x / (1.0f + __expf(-x)); }

__device__ __forceinline__ void gload_lds16(const void* g, void* l) {
  __builtin_amdgcn_global_load_lds(
      (const __attribute__((address_space(1))) void*)g,
      (__attribute__((address_space(3))) void*)l, 16, 0, 0);
}

// compiler emits v_cvt_pk_bf16_f32 for paired casts (RNE, same as manual)
__device__ __forceinline__ u32x4 pack8(const f32x4& a, const f32x4& b) {
  union { __bf16 h[8]; u32x4 u; } p;
  p.h[0] = (__bf16)a[0]; p.h[1] = (__bf16)a[1];
  p.h[2] = (__bf16)a[2]; p.h[3] = (__bf16)a[3];
  p.h[4] = (__bf16)b[0]; p.h[5] = (__bf16)b[1];
  p.h[6] = (__bf16)b[2]; p.h[7] = (__bf16)b[3];
  return p.u;
}
__device__ __forceinline__ unsigned short f2bfc(float f) {
  union { __bf16 h; unsigned short s; } u; u.h = (__bf16)f; return u.s;
}

// ---------------- prep: tiled transpose W->Wt bf16, zero tarval --------------
__global__ __launch_bounds__(256) void prep_kernel(
    const float* __restrict__ W1, const float* __restrict__ W2,
    unsigned short* __restrict__ Wt1, unsigned short* __restrict__ Wt2,
    float* __restrict__ tarval) {
  int b = blockIdx.x;
  if (b < 128) {
    const float* W = (b < 64) ? W1 : W2;
    unsigned short* Wt = (b < 64) ? Wt1 : Wt2;
    int tb = b & 63;
    int tk = (tb >> 3) * 64;
    int tn = (tb & 7) * 64;
    __shared__ float tile[64][65];
    int tx = threadIdx.x & 63;
    int ty4 = threadIdx.x >> 6;
#pragma unroll
    for (int i = 0; i < 16; ++i) {
      int row = ty4 * 16 + i;
      tile[row][tx] = W[(size_t)(tk + row) * 512 + tn + tx];
    }
    __syncthreads();
#pragma unroll
    for (int i = 0; i < 16; ++i) {
      int nrow = ty4 * 16 + i;
      Wt[(size_t)(tn + nrow) * 512 + tk + tx] = f2bf(tile[tx][nrow]);
    }
  } else {
    int id = (b - 128) * 256 + threadIdx.x;
#pragma unroll
    for (int i = 0; i < 17; ++i) {
      int idx = id + i * 4096;
      if (idx < MROWS) tarval[idx] = 0.0f;
    }
  }
}

// XCD-aware tile mapping: 4 col-blocks of one row-tile are consecutive per-XCD.
__device__ __forceinline__ void tile_map(int bid, int& rb, int& cb) {
  int xcd = bid & 7;
  int idx = bid >> 3;
  rb = xcd * 65 + (idx >> 2);
  cb = idx & 3;
}

// ---------------- GEMM1: A=feat f32 (reg convert), B=Wt1 bf16, BK=32 --------
__global__ __launch_bounds__(256, 4) void gemm1_kernel(
    const float* __restrict__ A, const unsigned short* __restrict__ Bt,
    const float* __restrict__ bias, unsigned short* __restrict__ Hout) {
  __shared__ __align__(16) unsigned char lds[32768];  // [2][A 8K | B 8K]

  int rb, cb; tile_map(blockIdx.x, rb, cb);
  const int m0 = rb * 128, n0 = cb * 128;
  const int tid = threadIdx.x;
  const int lane = tid & 63, w = tid >> 6;
  const int wr = w >> 1, wc = w & 1;
  const int q = lane >> 4, r = lane & 15;

  // staging coords: thread covers granules {tid, 256+tid} (rows srow, 64+srow)
  const int srow = tid >> 2;
  const int scol = (tid & 3) * 8;
  const float* a_src0 = A + (size_t)(m0 + srow) * 512 + scol;
  const float* a_src1 = A + (size_t)(m0 + 64 + srow) * 512 + scol;
  const unsigned short* b_src0 = Bt + (size_t)(n0 + srow) * 512 + scol;
  const unsigned short* b_src1 = Bt + (size_t)(n0 + 64 + srow) * 512 + scol;

  // frag read byte offsets (linear, conflict-free at 64B row stride)
  unsigned int a_off[4], b_off[4];
#pragma unroll
  for (int m = 0; m < 4; ++m) a_off[m] = (unsigned)(wr * 64 + m * 16 + r) * 64 + q * 16;
#pragma unroll
  for (int n = 0; n < 4; ++n) b_off[n] = 8192u + (unsigned)(wc * 64 + n * 16 + r) * 64 + q * 16;

  f32x4 acc[4][4] = {};
  f32x4 pa[4];

  // ---- prologue: pa(0); B(0)->buf0; B(1)->buf1; pack A(0)->buf0 ----
  pa[0] = *(const f32x4*)(a_src0);     pa[1] = *(const f32x4*)(a_src0 + 4);
  pa[2] = *(const f32x4*)(a_src1);     pa[3] = *(const f32x4*)(a_src1 + 4);
  gload_lds16(b_src0, lds + 8192 + w * 1024);
  gload_lds16(b_src1, lds + 12288 + w * 1024);
  gload_lds16(b_src0 + 32, lds + 16384 + 8192 + w * 1024);
  gload_lds16(b_src1 + 32, lds + 16384 + 12288 + w * 1024);
  *(u32x4*)(lds + tid * 16)        = pack8(pa[0], pa[1]);  // waits pa (vmcnt 4)
  *(u32x4*)(lds + 4096 + tid * 16) = pack8(pa[2], pa[3]);

#pragma unroll
  for (int t = 0; t < 16; ++t) {
    if (t < 15) asm volatile("s_waitcnt vmcnt(2) lgkmcnt(0)" ::: "memory");
    else        asm volatile("s_waitcnt vmcnt(0) lgkmcnt(0)" ::: "memory");
    __builtin_amdgcn_s_barrier();

    unsigned char* buf = lds + (t & 1) * 16384;

    if (t < 15) {               // pa(t+1), consumed at this iter's end
      const int ks = (t + 1) * 32;
      pa[0] = *(const f32x4*)(a_src0 + ks); pa[1] = *(const f32x4*)(a_src0 + ks + 4);
      pa[2] = *(const f32x4*)(a_src1 + ks); pa[3] = *(const f32x4*)(a_src1 + ks + 4);
    }

    bf16x8 af[4], bfr[4];
#pragma unroll
    for (int m = 0; m < 4; ++m) af[m] = *(const bf16x8*)(buf + a_off[m]);
#pragma unroll
    for (int n = 0; n < 4; ++n) bfr[n] = *(const bf16x8*)(buf + b_off[n]);
    asm volatile("s_waitcnt lgkmcnt(0)" ::: "memory");
    __builtin_amdgcn_sched_barrier(0);
    __builtin_amdgcn_s_barrier();       // all waves done reading buf[t&1]

    if (t + 2 < 16) {                   // B(t+2) -> bufB[t&1], counted in flight
      const int ks2 = (t + 2) * 32;
      gload_lds16(b_src0 + ks2, buf + 8192 + w * 1024);
      gload_lds16(b_src1 + ks2, buf + 12288 + w * 1024);
    }
    if (t < 15) {                       // pack+write A(t+1) -> bufA[(t+1)&1]
      unsigned char* an = lds + ((t + 1) & 1) * 16384;
      *(u32x4*)(an + tid * 16)        = pack8(pa[0], pa[1]);
      *(u32x4*)(an + 4096 + tid * 16) = pack8(pa[2], pa[3]);
    }

#pragma unroll
    for (int m = 0; m < 4; ++m)
#pragma unroll
      for (int n = 0; n < 4; ++n)
        acc[m][n] = __builtin_amdgcn_mfma_f32_16x16x32_bf16(af[m], bfr[n], acc[m][n], 0, 0, 0);
  }

  // epilogue: bias + silu -> bf16 H1
#pragma unroll
  for (int n = 0; n < 4; ++n) {
    const int col = n0 + wc * 64 + n * 16 + r;
    const float bn = bias[col];
#pragma unroll
    for (int m = 0; m < 4; ++m) {
      const int rbase = m0 + wr * 64 + m * 16 + q * 4;
#pragma unroll
      for (int i = 0; i < 4; ++i)
        Hout[(size_t)(rbase + i) * 512 + col] = f2bfc(silu_f(acc[m][n][i] + bn));
    }
  }
}

// ---------------- GEMM2: A=H1 bf16, B=Wt2 bf16, BK=32, fused W3 reduce ------
__global__ __launch_bounds__(256, 4) void gemm2_kernel(
    const unsigned short* __restrict__ A, const unsigned short* __restrict__ Bt,
    const float* __restrict__ bias, const float* __restrict__ W3,
    float* __restrict__ tarval) {
  __shared__ __align__(16) unsigned char lds[32768];

  int rb, cb; tile_map(blockIdx.x, rb, cb);
  const int m0 = rb * 128, n0 = cb * 128;
  const int tid = threadIdx.x;
  const int lane = tid & 63, w = tid >> 6;
  const int wr = w >> 1, wc = w & 1;
  const int q = lane >> 4, r = lane & 15;

  const int srow = tid >> 2;
  const int scol = (tid & 3) * 8;
  const unsigned short* a_src0 = A + (size_t)(m0 + srow) * 512 + scol;
  const unsigned short* a_src1 = A + (size_t)(m0 + 64 + srow) * 512 + scol;
  const unsigned short* b_src0 = Bt + (size_t)(n0 + srow) * 512 + scol;
  const unsigned short* b_src1 = Bt + (size_t)(n0 + 64 + srow) * 512 + scol;

  unsigned int a_off[4], b_off[4];
#pragma unroll
  for (int m = 0; m < 4; ++m) a_off[m] = (unsigned)(wr * 64 + m * 16 + r) * 64 + q * 16;
#pragma unroll
  for (int n = 0; n < 4; ++n) b_off[n] = 8192u + (unsigned)(wc * 64 + n * 16 + r) * 64 + q * 16;

  f32x4 acc[4][4] = {};

  // ---- prologue: stage(0)->buf0, stage(1)->buf1 (4 gloads each) ----
  gload_lds16(a_src0, lds + w * 1024);
  gload_lds16(a_src1, lds + 4096 + w * 1024);
  gload_lds16(b_src0, lds + 8192 + w * 1024);
  gload_lds16(b_src1, lds + 12288 + w * 1024);
  gload_lds16(a_src0 + 32, lds + 16384 + w * 1024);
  gload_lds16(a_src1 + 32, lds + 16384 + 4096 + w * 1024);
  gload_lds16(b_src0 + 32, lds + 16384 + 8192 + w * 1024);
  gload_lds16(b_src1 + 32, lds + 16384 + 12288 + w * 1024);

#pragma unroll
  for (int t = 0; t < 16; ++t) {
    if (t < 15) asm volatile("s_waitcnt vmcnt(4)" ::: "memory");
    else        asm volatile("s_waitcnt vmcnt(0)" ::: "memory");
    __builtin_amdgcn_s_barrier();

    unsigned char* buf = lds + (t & 1) * 16384;

    bf16x8 af[4], bfr[4];
#pragma unroll
    for (int m = 0; m < 4; ++m) af[m] = *(const bf16x8*)(buf + a_off[m]);
#pragma unroll
    for (int n = 0; n < 4; ++n) bfr[n] = *(const bf16x8*)(buf + b_off[n]);
    asm volatile("s_waitcnt lgkmcnt(0)" ::: "memory");
    __builtin_amdgcn_sched_barrier(0);
    __builtin_amdgcn_s_barrier();

    if (t + 2 < 16) {                   // stage(t+2) -> buf[t&1]
      const int ks2 = (t + 2) * 32;
      gload_lds16(a_src0 + ks2, buf + w * 1024);
      gload_lds16(a_src1 + ks2, buf + 4096 + w * 1024);
      gload_lds16(b_src0 + ks2, buf + 8192 + w * 1024);
      gload_lds16(b_src1 + ks2, buf + 12288 + w * 1024);
    }

#pragma unroll
    for (int m = 0; m < 4; ++m)
#pragma unroll
      for (int n = 0; n < 4; ++n)
        acc[m][n] = __builtin_amdgcn_mfma_f32_16x16x32_bf16(af[m], bfr[n], acc[m][n], 0, 0, 0);
  }

  // epilogue: silu(acc+b2) * W3[col], 16-lane shuffle reduce, atomic per row
#pragma unroll
  for (int m = 0; m < 4; ++m) {
    float ps0 = 0.f, ps1 = 0.f, ps2 = 0.f, ps3 = 0.f;
#pragma unroll
    for (int n = 0; n < 4; ++n) {
      const int col = n0 + wc * 64 + n * 16 + r;
      const float bn = bias[col];
      const float w3 = W3[col];
      ps0 += silu_f(acc[m][n][0] + bn) * w3;
      ps1 += silu_f(acc[m][n][1] + bn) * w3;
      ps2 += silu_f(acc[m][n][2] + bn) * w3;
      ps3 += silu_f(acc[m][n][3] + bn) * w3;
    }
    float ps[4] = {ps0, ps1, ps2, ps3};
#pragma unroll
    for (int i = 0; i < 4; ++i) {
      float v = ps[i];
      v += __shfl_xor(v, 1);
      v += __shfl_xor(v, 2);
      v += __shfl_xor(v, 4);
      v += __shfl_xor(v, 8);
      if (r == 0) {
        int row = m0 + wr * 64 + m * 16 + q * 4 + i;
        atomicAdd(&tarval[row], v);
      }
    }
  }
}

// ------- scan: suffix-composition lambda-return, log-depth shuffle ----------
// r_t = i_t + c_t * r_{t+1}; compose (i1,c1)o(i2,c2) = (i1 + c1*i2, c1*c2)
__global__ __launch_bounds__(256) void scan_kernel(
    const float* __restrict__ tarval, const float* __restrict__ reward,
    const float* __restrict__ cont, const float* __restrict__ voffset,
    const float* __restrict__ vscale, const float* __restrict__ b3,
    float* __restrict__ out) {
  const int row = blockIdx.x * 4 + (threadIdx.x >> 6);  // one wave per batch row
  const int t = threadIdx.x & 63;                       // maps to orig t+1
  const float vs = vscale[0], vo = voffset[0], bb = b3[0];
  const int g = row * 65 + 1 + t;
  const float tv = (tarval[g] + bb) * vs + vo;
  const float dt = cont[g] * DISCF;
  float ci = reward[g] + (1.0f - LAMF) * dt * tv;
  float cc = dt * LAMF;
  const float boot = __shfl(tv, 63, 64);
#pragma unroll
  for (int off = 1; off < 64; off <<= 1) {
    float i2 = __shfl_down(ci, off, 64);
    float c2 = __shfl_down(cc, off, 64);
    if (t + off < 64) { ci = ci + cc * i2; cc = cc * c2; }
  }
  out[row * 64 + t] = ci + cc * boot;
}

extern "C" void kernel_launch(void* const* d_in, const int* in_sizes, int n_in,
                              void* d_out, int out_size, void* d_ws, size_t ws_size,
                              hipStream_t stream) {
  const float* feat    = (const float*)d_in[0];
  const float* reward  = (const float*)d_in[1];
  const float* cont    = (const float*)d_in[2];
  const float* voffset = (const float*)d_in[3];
  const float* vscale  = (const float*)d_in[4];
  const float* W1s = (const float*)d_in[11];
  const float* b1s = (const float*)d_in[12];
  const float* W2s = (const float*)d_in[13];
  const float* b2s = (const float*)d_in[14];
  const float* W3s = (const float*)d_in[15];
  const float* b3s = (const float*)d_in[16];

  char* ws = (char*)d_ws;
  unsigned short* Wt1 = (unsigned short*)ws;                   // 512 KB
  unsigned short* Wt2 = (unsigned short*)(ws + (512u << 10));  // 512 KB
  float* tarval       = (float*)(ws + (1024u << 10));          // 266 240 B
  unsigned short* H1  = (unsigned short*)(ws + (2048u << 10)); // 68 157 440 B

  prep_kernel<<<144, 256, 0, stream>>>(W1s, W2s, Wt1, Wt2, tarval);
  gemm1_kernel<<<RBLK * 4, 256, 0, stream>>>(feat, Wt1, b1s, H1);
  gemm2_kernel<<<RBLK * 4, 256, 0, stream>>>(H1, Wt2, b2s, W3s, tarval);
  scan_kernel<<<256, 256, 0, stream>>>(tarval, reward, cont, voffset, vscale, b3s,
                                       (float*)d_out);
}